// Round 3
// baseline (31.752 us; speedup 1.0000x reference)
//
#include <hip/hip_runtime.h>

#define NF 17
#define ED 16
#define NN 23
#define RPB 64     // rows per block
#define BLK 256
#define SROWS 162  // total rows of the 11 small-vocab fields
#define SSTR 20    // padded floats per LDS table row (80 B, 16B-aligned)

__global__ __launch_bounds__(BLK) void ffm_fwd_kernel(
    const int* __restrict__ x_cat,
    const float* __restrict__ x_num,
    const float* __restrict__ table,
    const float* __restrict__ W_num,
    const float* __restrict__ bias,
    float* __restrict__ out,
    int nrows)
{
    __shared__ float lds_tab[SROWS * SSTR];  // 12960 B: small-field embedding rows
    __shared__ int   lds_cat[RPB * NF];      // 4352 B
    __shared__ float lds_num[RPB * NN];      // 5888 B
    __shared__ float wsum[NN];

    const int tid = threadIdx.x;

    // colsum of W_num
    if (tid < NN) {
        float a = 0.f;
        #pragma unroll
        for (int d = 0; d < ED; ++d) a += W_num[d * NN + tid];
        wsum[tid] = a;
    }

    // Stage this block's x_cat / x_num, coalesced.
    {
        const int cbase = blockIdx.x * (RPB * NF);
        for (int i = tid; i < RPB * NF; i += BLK) lds_cat[i] = x_cat[cbase + i];
        const int nbase = blockIdx.x * (RPB * NN);
        for (int i = tid; i < RPB * NN; i += BLK) lds_num[i] = x_num[nbase + i];
    }

    // Stage the 11 small-vocab fields' table slices into LDS (162 rows).
    // packed-row boundaries and corresponding global table row bases:
    {
        const int lb[12] = {0, 50, 53, 63, 83, 85, 87, 91, 95, 145, 155, 162};
        const int gb[11] = {500, 650, 1000653, 1000663, 1000783, 1000785,
                            1001788, 1001792, 1001796, 1003846, 1003856};
        for (int i = tid; i < SROWS * 4; i += BLK) {
            const int r = i >> 2, q = i & 3;
            int grow = 0;
            #pragma unroll
            for (int k = 0; k < 11; ++k)
                grow = (r >= lb[k] && r < lb[k + 1]) ? (gb[k] + (r - lb[k])) : grow;
            const float4 v = *(const float4*)(table + (size_t)grow * ED + q * 4);
            *(float4*)&lds_tab[r * SSTR + q * 4] = v;
        }
    }
    __syncthreads();

    const int rl  = tid >> 2;   // local row 0..63
    const int g   = tid & 3;    // dim-group: dims [4g, 4g+4)
    const int row = blockIdx.x * RPB + rl;
    if (row >= nrows) return;

    // Big-vocab fields gathered from global (L2/L3): f0,f2,f4,f7,f10,f14
    const int bigf[6]   = {0, 2, 4, 7, 10, 14};
    const int bigoff[6] = {0, 550, 653, 1000683, 1000787, 1001846};
    float4 bv[6];
    #pragma unroll
    for (int k = 0; k < 6; ++k) {
        const int idx = lds_cat[rl * NF + bigf[k]] + bigoff[k];
        bv[k] = *(const float4*)(table + (size_t)idx * ED + g * 4);
    }

    float s0 = 0.f, s1 = 0.f, s2 = 0.f, s3 = 0.f, sq = 0.f;

    // Small fields from LDS (overlaps with the global gathers' latency)
    const int smf[11] = {1, 3, 5, 6, 8, 9, 11, 12, 13, 15, 16};
    const int smb[11] = {0, 50, 53, 63, 83, 85, 87, 91, 95, 145, 155};
    #pragma unroll
    for (int k = 0; k < 11; ++k) {
        const int r = smb[k] + lds_cat[rl * NF + smf[k]];
        const float4 v = *(const float4*)&lds_tab[r * SSTR + g * 4];
        s0 += v.x; s1 += v.y; s2 += v.z; s3 += v.w;
        sq += v.x * v.x + v.y * v.y + v.z * v.z + v.w * v.w;
    }

    // numeric-linear term while globals are still in flight
    float lin = 0.f;
    #pragma unroll
    for (int j = g; j < NN; j += 4) lin += lds_num[rl * NN + j] * wsum[j];

    // consume the global gathers
    #pragma unroll
    for (int k = 0; k < 6; ++k) {
        const float4 v = bv[k];
        s0 += v.x; s1 += v.y; s2 += v.z; s3 += v.w;
        sq += v.x * v.x + v.y * v.y + v.z * v.z + v.w * v.w;
    }

    float ssum = s0 + s1 + s2 + s3;
    float ss2  = s0 * s0 + s1 * s1 + s2 * s2 + s3 * s3;

    #pragma unroll
    for (int m = 1; m <= 2; m <<= 1) {
        ssum += __shfl_xor(ssum, m);
        ss2  += __shfl_xor(ss2, m);
        sq   += __shfl_xor(sq, m);
        lin  += __shfl_xor(lin, m);
    }

    if (g == 0) out[row] = bias[0] + ssum + lin + 0.5f * (ss2 - sq);
}

extern "C" void kernel_launch(void* const* d_in, const int* in_sizes, int n_in,
                              void* d_out, int out_size, void* d_ws, size_t ws_size,
                              hipStream_t stream) {
    const int*   x_cat = (const int*)  d_in[0];
    const float* x_num = (const float*)d_in[1];
    const float* table = (const float*)d_in[2];
    const float* W_num = (const float*)d_in[3];
    const float* bias  = (const float*)d_in[4];
    float* out = (float*)d_out;

    const int nrows = out_size;                 // 262144
    const int grid = (nrows + RPB - 1) / RPB;   // 4096
    ffm_fwd_kernel<<<grid, BLK, 0, stream>>>(x_cat, x_num, table, W_num, bias, out, nrows);
}